// Round 1
// 203.481 us; speedup vs baseline: 1.0060x; 1.0060x over previous
//
#include <hip/hip_runtime.h>
#include <math.h>

#define FHW   32
#define NA    9
#define NBOX  9216          // 32*32*9
#define C1    256
#define C2    512
#define KTOT  2304          // 256*9
#define KS    8             // split-K factor
#define KCH   (KTOT / KS)   // 288
#define CAP   64            // max stored in-neighbors per box
#define ECAP  16384         // LDS CSR edge capacity (overflow -> global fallback)
#define ROUNDS 96

struct AnchorWH { float w[NA]; float h[NA]; };

// ---------------- workspace layout (bytes, all 256-aligned) ----------------
#define FP_OFF    0u                      // padded feature 256*34*34 f32
#define WT_OFF    1183744u                // transposed weights 2304*512 f32 (tap-major rows)
#define HP_OFF    5902336u                // split-K partials 8*1024*512 f32
#define BOX_OFF   22679552u               // boxes 9216*4 f32
#define SC_OFF    22827008u               // scores 9216 f32
#define VL_OFF    22863872u               // vlist 9216 u32
#define DEG_OFF   22900736u               // deg 9216 u32
#define ADJ_OFF   22937600u               // adj 9216*CAP u16
#define KEEP_OFF  24117248u               // keep 9216 u32
#define NV_OFF    24154112u               // valid count u32

// ---------------------------------------------------------------------------
// Kernel 1 (merged): blocks [0,1156): zero-pad feature into Fp[256][34][34],
// zero deg[]/keep[]/nv. blocks [1156,2308): transpose conv1_w -> Wt.
// Wt row ordering is TAP-MAJOR: row k' = kap*256 + c  (kap = 3*dy+dx).
// With 32 | 256, every BK=32 GEMM K-tile then has a single uniform tap ->
// A-staging addressing in k_gemm becomes base + kk*1156 (no div/mod).
// ---------------------------------------------------------------------------
__global__ __launch_bounds__(256) void k_prep(const float* __restrict__ fin,
                                              float* __restrict__ Fp,
                                              unsigned int* __restrict__ deg,
                                              unsigned int* __restrict__ keepG,
                                              unsigned int* __restrict__ nv,
                                              const float* __restrict__ w1,
                                              float* __restrict__ Wt) {
    if (blockIdx.x < 1156) {
        int idx = blockIdx.x * 256 + threadIdx.x;
        if (idx < 256 * 34 * 34) {
            int c   = idx / 1156;
            int rem = idx - c * 1156;
            int yy  = rem / 34;
            int xx  = rem - yy * 34;
            float v = 0.f;
            if (yy >= 1 && yy <= 32 && xx >= 1 && xx <= 32)
                v = fin[c * 1024 + (yy - 1) * 32 + (xx - 1)];
            Fp[idx] = v;
        }
        if (idx < NBOX) { deg[idx] = 0u; keepG[idx] = 0u; }
        if (idx == 0)   *nv = 0u;
    } else {
        __shared__ float tile[32][33];
        int tb  = blockIdx.x - 1156;      // 72*16 tiles
        int k0  = (tb % 72) * 32;
        int oc0 = (tb / 72) * 32;
        int t   = threadIdx.x;
        int r0 = t >> 5, c = t & 31;
        #pragma unroll
        for (int i = 0; i < 4; ++i) {
            int r = r0 + 8 * i;                       // oc-local
            tile[r][c] = w1[(oc0 + r) * KTOT + k0 + c];
        }
        __syncthreads();
        #pragma unroll
        for (int i = 0; i < 4; ++i) {
            int kk  = r0 + 8 * i;                     // k-local
            int k   = k0 + kk;                        // source k = c*9 + kap
            int ch  = k / 9;
            int kap = k - ch * 9;
            Wt[(kap * 256 + ch) * C2 + oc0 + c] = tile[c][kk];  // tap-major row
        }
    }
}

// ---------------------------------------------------------------------------
// Kernel 2: split-K fp32 GEMM. 64x128 tile, BK=32, 256 threads, 4x8 microtile.
// Grid 512 = 2 blocks/CU. Register double-buffered staging (issue global
// loads for tile t+1 BEFORE computing tile t), tap-major K so A addressing
// is uniform-base + kk*1156. 18 barriers total (2/tile x 9 tiles).
// ---------------------------------------------------------------------------
__global__ __launch_bounds__(256, 2) void k_gemm(const float* __restrict__ Fp,
                                                 const float* __restrict__ Wt,
                                                 float* __restrict__ hp) {
    const int id = blockIdx.x;
    const int bx = id >> 5, g = id & 31;
    const int by = g >> 3, kz = g & 7;
    const int p0  = bx * 64;
    const int oc0 = by * 128;
    const int k0b = kz * KCH;
    const int t  = threadIdx.x;
    const int ty = t >> 4, tx = t & 15;

    __shared__ float As[32][64];     // 8 KB
    __shared__ float Bs[32][128];    // 16 KB

    // thread-constant staging coordinates
    const int pp   = t & 63;                 // pixel-local (same for all 8 A elems)
    const int kkA0 = t >> 6;                 // A k-local base (+4*i)
    const int kkB0 = t >> 5;                 // B k-local base (+8*i)
    const int c4   = (t & 31) << 2;          // B oc-local float4 base
    const int yx   = ((p0 + pp) >> 5) * 34 + ((p0 + pp) & 31);

    float acc[4][8];
    #pragma unroll
    for (int r = 0; r < 4; ++r)
        #pragma unroll
        for (int c = 0; c < 8; ++c) acc[r][c] = 0.f;

    float  aS[8];
    float4 bS[4];

    // gather K-tile starting at global-k' s into registers (no LDS touch)
    auto LOAD = [&](int s) {
        int tap = s >> 8, c0 = s & 255;      // uniform per block
        int dy  = (tap * 11) >> 5;           // tap/3 for tap<9
        int dx  = tap - 3 * dy;
        const float* ab = Fp + (c0 * 34 + dy) * 34 + dx + yx;
        #pragma unroll
        for (int i = 0; i < 8; ++i) aS[i] = ab[(kkA0 + 4 * i) * 1156];
        const float* bb = Wt + (s + kkB0) * C2 + oc0 + c4;
        #pragma unroll
        for (int i = 0; i < 4; ++i) bS[i] = *(const float4*)(bb + (8 * i) * C2);
    };

    LOAD(k0b);
    #pragma unroll 1
    for (int kt = 0; kt < KCH; kt += 32) {
        __syncthreads();                     // prev-tile compute done (reads)
        #pragma unroll
        for (int i = 0; i < 8; ++i) As[kkA0 + 4 * i][pp] = aS[i];
        #pragma unroll
        for (int i = 0; i < 4; ++i) *(float4*)&Bs[kkB0 + 8 * i][c4] = bS[i];
        __syncthreads();
        if (kt + 32 < KCH) LOAD(k0b + kt + 32);   // in flight across compute
        #pragma unroll
        for (int kk = 0; kk < 32; ++kk) {
            float a[4], b[8];
            *(float4*)&a[0] = *(const float4*)&As[kk][ty * 4];
            *(float4*)&b[0] = *(const float4*)&Bs[kk][tx * 4];
            *(float4*)&b[4] = *(const float4*)&Bs[kk][tx * 4 + 64];
            #pragma unroll
            for (int r = 0; r < 4; ++r)
                #pragma unroll
                for (int c = 0; c < 8; ++c) acc[r][c] += a[r] * b[c];
        }
    }
    #pragma unroll
    for (int r = 0; r < 4; ++r) {
        int p = p0 + ty * 4 + r;
        float* dst = hp + ((kz * 1024 + p) * C2 + oc0 + tx * 4);
        *(float4*)dst        = *(float4*)&acc[r][0];
        *(float4*)(dst + 64) = *(float4*)&acc[r][4];
    }
}

// ---------------------------------------------------------------------------
// Kernel 3: heads, 4 pixels/block (256 blocks). Split-K reduce + relu ->
// 45 dots/pixel -> sigmoid/decode/clip/valid -> compact valid list.
// ---------------------------------------------------------------------------
__global__ __launch_bounds__(256) void k_heads(const float* __restrict__ hp,
                                               const float* __restrict__ b1,
                                               const float* __restrict__ w2,
                                               const float* __restrict__ b2,
                                               const float* __restrict__ w3,
                                               const float* __restrict__ b3,
                                               float* __restrict__ boxes,
                                               float* __restrict__ scoresG,
                                               unsigned int* __restrict__ nv,
                                               unsigned int* __restrict__ vlist,
                                               AnchorWH awh) {
    const int p0 = blockIdx.x * 4;
    const int t  = threadIdx.x;
    __shared__ float hrow[4][C2];
    __shared__ float arr[4][45];

    #pragma unroll
    for (int px = 0; px < 4; ++px) {
        int p = p0 + px;
        #pragma unroll
        for (int i = 0; i < 2; ++i) {
            int c = t + 256 * i;
            float s = b1[c];
            #pragma unroll
            for (int ks = 0; ks < KS; ++ks) s += hp[(ks * 1024 + p) * C2 + c];
            hrow[px][c] = fmaxf(s, 0.f);
        }
    }
    __syncthreads();

    const int w = t >> 6, lane = t & 63;
    for (int job = w; job < 180; job += 4) {
        int px = job / 45, j = job - px * 45;
        const float* wp = (j < 9) ? (w2 + j * C2) : (w3 + (j - 9) * C2);
        float s = 0.f;
        #pragma unroll
        for (int i = 0; i < 8; ++i) s += hrow[px][lane + 64 * i] * wp[lane + 64 * i];
        #pragma unroll
        for (int d = 1; d < 64; d <<= 1) s += __shfl_xor(s, d, 64);
        if (lane == 0) arr[px][j] = s;
    }
    __syncthreads();

    if (t < 36) {
        int px = t / 9, a = t - px * 9;
        int p = p0 + px;
        float logit = arr[px][a] + b2[a];
        float score = 1.f / (1.f + expf(-logit));
        float o0 = arr[px][9 + a * 4 + 0] + b3[a * 4 + 0];
        float o1 = arr[px][9 + a * 4 + 1] + b3[a * 4 + 1];
        float o2 = arr[px][9 + a * 4 + 2] + b3[a * 4 + 2];
        float o3 = arr[px][9 + a * 4 + 3] + b3[a * 4 + 3];
        int y = p >> 5, x = p & 31;
        float ax = (x + 0.5f) * 16.f, ay = (y + 0.5f) * 16.f;
        float aw = awh.w[a], ah = awh.h[a];
        float cx = ax + o0 * aw;
        float cy = ay + o1 * ah;
        float bw = aw * expf(o2);
        float bh = ah * expf(o3);
        float x1 = fminf(fmaxf(cx - bw * 0.5f, 0.f), 512.f);
        float y1 = fminf(fmaxf(cy - bh * 0.5f, 0.f), 512.f);
        float x2 = fminf(fmaxf(cx + bw * 0.5f, 0.f), 512.f);
        float y2 = fminf(fmaxf(cy + bh * 0.5f, 0.f), 512.f);
        int n = p * 9 + a;
        float4 bx4; bx4.x = x1; bx4.y = y1; bx4.z = x2; bx4.w = y2;
        ((float4*)boxes)[n] = bx4;
        scoresG[n] = score;
        bool valid = (x2 - x1 >= 0.001f) && (y2 - y1 >= 0.001f) && (score >= 0.5f);
        if (valid) {
            unsigned int ci = atomicAdd(nv, 1u);
            vlist[ci] = (unsigned int)n;
        }
    }
}

// ---------------------------------------------------------------------------
// Kernel 4: sparse adjacency among valid boxes (IoU>0.7 pairs; higher-priority
// endpoint stored into lower-priority node's in-list). Triangular 128x128.
// ---------------------------------------------------------------------------
__global__ __launch_bounds__(256) void k_adj(const unsigned int* __restrict__ nvp,
                                             const unsigned int* __restrict__ vlist,
                                             const float* __restrict__ boxes,
                                             const float* __restrict__ scoresG,
                                             unsigned int* __restrict__ deg,
                                             unsigned short* __restrict__ adj) {
    const int Nv = (int)*nvp;
    int b = blockIdx.x;
    int tv = (int)(sqrtf(2.f * b + 0.25f) - 0.5f);
    while ((tv + 1) * (tv + 2) / 2 <= b) tv++;
    while (tv * (tv + 1) / 2 > b) tv--;
    int tu = b - tv * (tv + 1) / 2;
    if (tv * 128 >= Nv) return;

    __shared__ float4 ub[128], vb[128];
    __shared__ float  us[128], vs[128];
    __shared__ int    uo[128], vo[128];
    int t = threadIdx.x;
    if (t < 128) {
        int gi = tu * 128 + t;
        if (gi < Nv) { int n = (int)vlist[gi]; ub[t] = ((const float4*)boxes)[n]; us[t] = scoresG[n]; uo[t] = n; }
        else us[t] = -1.f;
    } else {
        int tt = t - 128;
        int gj = tv * 128 + tt;
        if (gj < Nv) { int n = (int)vlist[gj]; vb[tt] = ((const float4*)boxes)[n]; vs[tt] = scoresG[n]; vo[tt] = n; }
        else vs[tt] = -1.f;
    }
    __syncthreads();

    for (int s = 0; s < 64; ++s) {
        int q  = t + 256 * s;          // 16384 pairs
        int i  = q >> 7, jj = q & 127;
        if (tu == tv && i >= jj) continue;
        float su = us[i], sv = vs[jj];
        if (su < 0.f || sv < 0.f) continue;
        float4 bu = ub[i], bv = vb[jj];
        float au = (bu.z - bu.x) * (bu.w - bu.y);
        float av = (bv.z - bv.x) * (bv.w - bv.y);
        float ix1 = fmaxf(bu.x, bv.x), iy1 = fmaxf(bu.y, bv.y);
        float ix2 = fminf(bu.z, bv.z), iy2 = fminf(bu.w, bv.w);
        float inter = fmaxf(ix2 - ix1, 0.f) * fmaxf(iy2 - iy1, 0.f);
        float uni = au + av - inter;
        float iou = inter / fmaxf(uni, 1e-9f);
        if (iou > 0.7f) {
            int gi = tu * 128 + i, gj = tv * 128 + jj;
            bool uHigh = (su > sv) || (su == sv && uo[i] < vo[jj]);
            int lower = uHigh ? gj : gi;
            int upper = uHigh ? gi : gj;
            unsigned int slot = atomicAdd(&deg[lower], 1u);
            if (slot < CAP) adj[lower * CAP + slot] = (unsigned short)upper;
        }
    }
}

// ---------------------------------------------------------------------------
// Kernel 5: single-block MIS peeling == exact greedy NMS.
// ---------------------------------------------------------------------------
__global__ __launch_bounds__(512) void k_peel(const unsigned int* __restrict__ nvp,
                                              const unsigned int* __restrict__ vlist,
                                              const unsigned int* __restrict__ degG,
                                              const unsigned short* __restrict__ adjG,
                                              unsigned int* __restrict__ keepG) {
    __shared__ unsigned short offL[NBOX + 2];    // 18436 B
    __shared__ unsigned char  st[NBOX];          // 9216 B
    __shared__ unsigned short csr[ECAP];         // 32768 B
    __shared__ unsigned int   scratch[512];      // 2048 B
    __shared__ unsigned char  flags[ROUNDS];     // 96 B
    const int t  = threadIdx.x;
    const int Nv = (int)*nvp;
    const int chunk = (Nv + 511) / 512;          // <= 18
    const int i0 = t * chunk;
    const int i1 = (i0 + chunk < Nv) ? (i0 + chunk) : Nv;

    if (t < ROUNDS) flags[t] = 0;

    // ---- degrees (stashed in st) + local sum ----
    unsigned int lsum = 0;
    for (int i = i0; i < i1; ++i) {
        unsigned int d = degG[i];
        if (d > CAP) d = CAP;
        st[i] = (unsigned char)d;
        lsum += d;
    }
    scratch[t] = lsum;
    __syncthreads();
    for (int ofs = 1; ofs < 512; ofs <<= 1) {    // Hillis-Steele inclusive
        unsigned int v = (t >= ofs) ? scratch[t - ofs] : 0u;
        __syncthreads();
        scratch[t] += v;
        __syncthreads();
    }
    if (t == 511) {
        unsigned int tot = scratch[511];
        offL[Nv] = (unsigned short)(tot < ECAP ? tot : ECAP);
    }
    // ---- offsets + LDS edge copy; decide deg-0 nodes; build active mask ----
    unsigned int amask = 0;
    {
        unsigned int off = scratch[t] - lsum;
        for (int i = i0; i < i1; ++i) {
            unsigned int o = (off < ECAP) ? off : ECAP;
            offL[i] = (unsigned short)o;
            int d = st[i];
            int ld = (int)ECAP - (int)o; if (ld > d) ld = d; if (ld < 0) ld = 0;
            for (int s = 0; s < ld; ++s)
                csr[o + s] = adjG[i * CAP + s];
            off += d;
            if (d == 0) st[i] = 1;               // isolated valid box -> kept
            else { st[i] = 0; amask |= 1u << (i - i0); }
        }
    }
    __syncthreads();

    // ---- peel rounds: 1 barrier each, active-only scan ----
    for (int r = 0; r < ROUNDS; ++r) {
        bool any = false;
        unsigned int m = amask;
        while (m) {
            int b = __ffs(m) - 1; m &= m - 1;
            int i = i0 + b;
            int o = offL[i], on = offL[i + 1];
            int d, ld;
            if (on < ECAP) { d = on - o; ld = d; }
            else {
            unsigned int dg = degG[i]; d = (dg > CAP) ? CAP : (int)dg;
                ld = (int)ECAP - o; if (ld < 0) ld = 0; if (ld > d) ld = d;
            }
            bool kseen = false, useen = false;
            for (int s = 0; s < d; ++s) {
                int j = (s < ld) ? (int)csr[o + s] : (int)adjG[i * CAP + s];
                unsigned char v = st[j];
                kseen |= (v == 1);
                useen |= (v == 0);
            }
            if (kseen)       { st[i] = 2; any = true; amask &= ~(1u << b); }
            else if (!useen) { st[i] = 1; any = true; amask &= ~(1u << b); }
        }
        if (any) flags[r] = 1;
        __syncthreads();
        if (!flags[r]) break;
    }

    // ---- scatter kept flags ----
    for (int i = i0; i < i1; ++i)
        if (st[i] == 1) keepG[vlist[i]] = 1u;
}

// ---------------------------------------------------------------------------
// Kernel 6: full-grid masked output write (9216 x 5).
// ---------------------------------------------------------------------------
__global__ __launch_bounds__(256) void k_out(const float* __restrict__ boxes,
                                             const float* __restrict__ scoresG,
                                             const unsigned int* __restrict__ keepG,
                                             float* __restrict__ out) {
    int n = blockIdx.x * 256 + threadIdx.x;
    if (n >= NBOX) return;
    float k = keepG[n] ? 1.f : 0.f;
    float4 b = ((const float4*)boxes)[n];
    out[n * 5 + 0] = b.x * k;
    out[n * 5 + 1] = b.y * k;
    out[n * 5 + 2] = b.z * k;
    out[n * 5 + 3] = b.w * k;
    out[n * 5 + 4] = scoresG[n] * k;
}

// ---------------------------------------------------------------------------
extern "C" void kernel_launch(void* const* d_in, const int* in_sizes, int n_in,
                              void* d_out, int out_size, void* d_ws, size_t ws_size,
                              hipStream_t stream) {
    const float* fin = (const float*)d_in[0];
    const float* w1  = (const float*)d_in[1];
    const float* b1  = (const float*)d_in[2];
    const float* w2  = (const float*)d_in[3];
    const float* b2  = (const float*)d_in[4];
    const float* w3  = (const float*)d_in[5];
    const float* b3  = (const float*)d_in[6];
    float* out = (float*)d_out;

    char* ws = (char*)d_ws;
    float*          Fp    = (float*)(ws + FP_OFF);
    float*          Wt    = (float*)(ws + WT_OFF);
    float*          hp    = (float*)(ws + HP_OFF);
    float*          boxes = (float*)(ws + BOX_OFF);
    float*          sc    = (float*)(ws + SC_OFF);
    unsigned int*   vlist = (unsigned int*)(ws + VL_OFF);
    unsigned int*   deg   = (unsigned int*)(ws + DEG_OFF);
    unsigned short* adj   = (unsigned short*)(ws + ADJ_OFF);
    unsigned int*   keepG = (unsigned int*)(ws + KEEP_OFF);
    unsigned int*   nv    = (unsigned int*)(ws + NV_OFF);

    AnchorWH awh;
    {
        const double sizes[3]  = {32.0, 64.0, 128.0};
        const double ratios[3] = {0.5, 1.0, 2.0};
        for (int si = 0; si < 3; ++si)
            for (int ri = 0; ri < 3; ++ri) {
                awh.w[si * 3 + ri] = (float)(sizes[si] / sqrt(ratios[ri]));
                awh.h[si * 3 + ri] = (float)(sizes[si] * sqrt(ratios[ri]));
            }
    }

    k_prep<<<dim3(1156 + 72 * 16), 256, 0, stream>>>(fin, Fp, deg, keepG, nv, w1, Wt);
    k_gemm<<<dim3(512), 256, 0, stream>>>(Fp, Wt, hp);
    k_heads<<<dim3(256), 256, 0, stream>>>(hp, b1, w2, b2, w3, b3, boxes, sc, nv, vlist, awh);
    k_adj<<<dim3(72 * 73 / 2), 256, 0, stream>>>(nv, vlist, boxes, sc, deg, adj);
    k_peel<<<dim3(1), 512, 0, stream>>>(nv, vlist, deg, adj, keepG);
    k_out<<<dim3((NBOX + 255) / 256), 256, 0, stream>>>(boxes, sc, keepG, out);
}